// Round 6
// baseline (520.907 us; speedup 1.0000x reference)
//
#include <hip/hip_runtime.h>
#include <math.h>

static constexpr int D = 64;
static constexpr int SCAN_BLOCKS = 256;
static constexpr int NPB = 64;   // nodes per coarse bin (dstLow = 6 bits)

typedef __bf16 bf16x8 __attribute__((ext_vector_type(8)));
typedef float f32x4 __attribute__((ext_vector_type(4)));

// ============================ common helpers ============================

__device__ __forceinline__ unsigned short f2bf(float f) {  // RNE
  unsigned u = __float_as_uint(f);
  return (unsigned short)((u + 0x7fffu + ((u >> 16) & 1u)) >> 16);
}
__device__ __forceinline__ float bf2f(unsigned short h) {
  return __uint_as_float((unsigned)h << 16);
}

// Monotone float max via int/uint atomics (works on LDS and global).
__device__ __forceinline__ void lds_max_f32(float* p, float v) {
  if (v >= 0.0f)
    atomicMax(reinterpret_cast<int*>(p), __float_as_int(v));
  else
    atomicMin(reinterpret_cast<unsigned int*>(p), __float_as_uint(v));
}

__device__ __forceinline__ void atomic_max_float(float* p, float v, float cur) {
  if (!(v > cur)) return;
  if (v >= 0.0f)
    atomicMax(reinterpret_cast<int*>(p), __float_as_int(v));
  else
    atomicMin(reinterpret_cast<unsigned int*>(p), __float_as_uint(v));
}

__global__ void k_init_neginf(float4* __restrict__ out, int n4) {
  int i = blockIdx.x * blockDim.x + threadIdx.x;
  if (i < n4) {
    float4 v;
    v.x = v.y = v.z = v.w = -INFINITY;
    out[i] = v;
  }
}

// x fp32 -> bf16, 4 elems/thread.
__global__ __launch_bounds__(256) void k_cvt(const float4* __restrict__ x,
                                             ushort2* __restrict__ xb, int n4) {
  for (int i = blockIdx.x * blockDim.x + threadIdx.x; i < n4;
       i += gridDim.x * blockDim.x) {
    const float4 v = x[i];
    ushort2 a, b;
    a.x = f2bf(v.x); a.y = f2bf(v.y);
    b.x = f2bf(v.z); b.y = f2bf(v.w);
    xb[i * 2] = a;
    xb[i * 2 + 1] = b;
  }
}

// ============================ MFMA precompute ============================
// yb[t][n][o] = bf16( b[t][o] + sum_k x[n][k] * W[t][k][o] ), t in {0,1}
__global__ __launch_bounds__(256) void k_gemm(
    const unsigned short* __restrict__ xb, const float* __restrict__ W,
    const float* __restrict__ b, unsigned short* __restrict__ yb, int nN) {
  const int lane = threadIdx.x & 63;
  const int wid = (blockIdx.x << 2) + (threadIdx.x >> 6);
  const int nWaves = gridDim.x << 2;
  const int kgrp = (lane >> 4) << 3;  // 0,8,16,24
  const int nsub = lane & 15;

  bf16x8 Bf[8][2];
  float bias[8];
#pragma unroll
  for (int nt = 0; nt < 8; ++nt) {
    const int t = nt >> 2;
    const int n = ((nt & 3) << 4) + nsub;
#pragma unroll
    for (int ks = 0; ks < 2; ++ks) {
      bf16x8 f;
#pragma unroll
      for (int e = 0; e < 8; ++e) {
        const int k = (ks << 5) + kgrp + e;
        f[e] = (__bf16)W[t * 4096 + k * 64 + n];
      }
      Bf[nt][ks] = f;
    }
    bias[nt] = b[t * 64 + n];
  }

  const int nChunks = (nN + 15) >> 4;
  for (int c = wid; c < nChunks; c += nWaves) {
    const int base = c << 4;
    const int arow = min(base + nsub, nN - 1);
    const bf16x8 a0 =
        *reinterpret_cast<const bf16x8*>(xb + (size_t)arow * 64 + kgrp);
    const bf16x8 a1 =
        *reinterpret_cast<const bf16x8*>(xb + (size_t)arow * 64 + 32 + kgrp);
#pragma unroll
    for (int nt = 0; nt < 8; ++nt) {
      f32x4 acc = {bias[nt], bias[nt], bias[nt], bias[nt]};
      acc = __builtin_amdgcn_mfma_f32_16x16x32_bf16(a0, Bf[nt][0], acc, 0, 0, 0);
      acc = __builtin_amdgcn_mfma_f32_16x16x32_bf16(a1, Bf[nt][1], acc, 0, 0, 0);
      const int t = nt >> 2;
      const int o = ((nt & 3) << 4) + nsub;
      const int rbase = base + ((lane >> 4) << 2);
#pragma unroll
      for (int r = 0; r < 4; ++r) {
        const int node = rbase + r;
        if (node < nN) yb[((size_t)t * nN + node) * 64 + o] = f2bf(acc[r]);
      }
    }
  }
}

// ============================ coarse binning ============================

__global__ void k_hist_coarse(const int* __restrict__ dst,
                              int* __restrict__ counts, int nE) {
  int i = blockIdx.x * blockDim.x + threadIdx.x;
  if (i < nE) atomicAdd(&counts[dst[i] >> 6], 1);
}

__global__ __launch_bounds__(256) void k_scan_partial(
    const int* __restrict__ counts, int* __restrict__ blockSums, int nN) {
  __shared__ int red[256];
  const int t = threadIdx.x;
  const int seg = (nN + gridDim.x - 1) / gridDim.x;
  const int beg = blockIdx.x * seg;
  const int end = min(beg + seg, nN);
  int s = 0;
  for (int i = beg + t; i < end; i += 256) s += counts[i];
  red[t] = s;
  __syncthreads();
  for (int d = 128; d > 0; d >>= 1) {
    if (t < d) red[t] += red[t + d];
    __syncthreads();
  }
  if (t == 0) blockSums[blockIdx.x] = red[0];
}

__global__ __launch_bounds__(256) void k_scan_block(
    int* __restrict__ blockSums, int* __restrict__ offs, int nN, int nBlocks) {
  __shared__ int sh[256];
  const int t = threadIdx.x;
  const int v = (t < nBlocks) ? blockSums[t] : 0;
  sh[t] = v;
  __syncthreads();
  for (int d = 1; d < 256; d <<= 1) {
    const int o = (t >= d) ? sh[t - d] : 0;
    __syncthreads();
    sh[t] += o;
    __syncthreads();
  }
  if (t < nBlocks) blockSums[t] = sh[t] - v;
  if (t == 255) offs[nN] = sh[255];
}

__global__ __launch_bounds__(256) void k_scan_write(
    const int* __restrict__ counts, const int* __restrict__ blockSums,
    int* __restrict__ offs, int* __restrict__ cursors, int nN) {
  __shared__ int sh[256];
  const int t = threadIdx.x;
  const int seg = (nN + gridDim.x - 1) / gridDim.x;
  const int beg = blockIdx.x * seg;
  const int end = min(beg + seg, nN);
  int carry = blockSums[blockIdx.x];
  for (int base = beg; base < end; base += 256) {
    const int i = base + t;
    const int v = (i < end) ? counts[i] : 0;
    sh[t] = v;
    __syncthreads();
    for (int d = 1; d < 256; d <<= 1) {
      const int o = (t >= d) ? sh[t - d] : 0;
      __syncthreads();
      sh[t] += o;
      __syncthreads();
    }
    const int excl = carry + sh[t] - v;
    if (i < end) {
      offs[i] = excl;
      cursors[i] = excl;
    }
    carry += sh[255];
    __syncthreads();
  }
}

// Record: src (bits 0-19) | type (bit 20) | dstLow (bits 21+). Requires
// nN < 2^20 (guarded in launcher).
__global__ void k_binscatter(const int* __restrict__ src,
                             const int* __restrict__ dst,
                             const int* __restrict__ ea,
                             int* __restrict__ cursors,
                             unsigned* __restrict__ binned, int nE) {
  int i = blockIdx.x * blockDim.x + threadIdx.x;
  if (i < nE) {
    const int d = dst[i];
    const int pos = atomicAdd(&cursors[d >> 6], 1);
    binned[pos] = (unsigned)src[i] | ((unsigned)ea[i] << 20) |
                  ((unsigned)(d & (NPB - 1)) << 21);
  }
}

// One block per bin: LDS [NPB][64] f32 acc owned exclusively by this block.
// Wave = one record/iter (lane = channel, 128B row gather), LDS atomic max,
// then one coalesced out write with -inf -> 0 fused.
__global__ __launch_bounds__(256) void k_reduce_bin(
    const int* __restrict__ offs, const unsigned* __restrict__ binned,
    const unsigned short* __restrict__ yb, float* __restrict__ out, int nN) {
  __shared__ float acc[NPB * 64];  // 16 KB
  const int t = threadIdx.x;
#pragma unroll
  for (int i = 0; i < NPB * 64 / 256; ++i) acc[t + i * 256] = -INFINITY;
  __syncthreads();

  const int bin = blockIdx.x;
  const int beg = offs[bin];
  const int cnt = offs[bin + 1] - beg;
  const int w = t >> 6;
  const int lane = t & 63;
  const int myBeg = beg + ((cnt * w) >> 2);
  const int myEnd = beg + ((cnt * (w + 1)) >> 2);

  int j = myBeg;
  for (; j + 3 < myEnd; j += 4) {
    const unsigned r0 = binned[j];
    const unsigned r1 = binned[j + 1];
    const unsigned r2 = binned[j + 2];
    const unsigned r3 = binned[j + 3];
    const float v0 = bf2f(yb[((size_t)((r0 >> 20) & 1) * nN + (r0 & 0xFFFFFu)) * 64 + lane]);
    const float v1 = bf2f(yb[((size_t)((r1 >> 20) & 1) * nN + (r1 & 0xFFFFFu)) * 64 + lane]);
    const float v2 = bf2f(yb[((size_t)((r2 >> 20) & 1) * nN + (r2 & 0xFFFFFu)) * 64 + lane]);
    const float v3 = bf2f(yb[((size_t)((r3 >> 20) & 1) * nN + (r3 & 0xFFFFFu)) * 64 + lane]);
    lds_max_f32(&acc[((r0 >> 21) << 6) + lane], v0);
    lds_max_f32(&acc[((r1 >> 21) << 6) + lane], v1);
    lds_max_f32(&acc[((r2 >> 21) << 6) + lane], v2);
    lds_max_f32(&acc[((r3 >> 21) << 6) + lane], v3);
  }
  for (; j < myEnd; ++j) {
    const unsigned r0 = binned[j];
    const float v0 = bf2f(yb[((size_t)((r0 >> 20) & 1) * nN + (r0 & 0xFFFFFu)) * 64 + lane]);
    lds_max_f32(&acc[((r0 >> 21) << 6) + lane], v0);
  }
  __syncthreads();

  const int nodeBase = bin * NPB;
  for (int f = t; f < NPB * 16; f += 256) {   // one float4 per f
    const int node = nodeBase + (f >> 4);
    if (node < nN) {
      float4 v = *reinterpret_cast<const float4*>(&acc[f * 4]);
      if (v.x == -INFINITY) v.x = 0.0f;
      if (v.y == -INFINITY) v.y = 0.0f;
      if (v.z == -INFINITY) v.z = 0.0f;
      if (v.w == -INFINITY) v.w = 0.0f;
      *reinterpret_cast<float4*>(&out[(size_t)node * 64 + (f & 15) * 4]) = v;
    }
  }
}

// ============================ fallback kernels ============================

__global__ void k_fixup(float4* __restrict__ out, int n4) {
  int i = blockIdx.x * blockDim.x + threadIdx.x;
  if (i < n4) {
    float4 v = out[i];
    if (v.x == -INFINITY) v.x = 0.0f;
    if (v.y == -INFINITY) v.y = 0.0f;
    if (v.z == -INFINITY) v.z = 0.0f;
    if (v.w == -INFINITY) v.w = 0.0f;
    out[i] = v;
  }
}

__global__ __launch_bounds__(256) void k_edge_direct(
    const float* __restrict__ x, const float* __restrict__ W,
    const float* __restrict__ b, const int* __restrict__ ei,
    const int* __restrict__ ea, float* __restrict__ out, int nEdges) {
  __shared__ float Wl[2 * D * D];
  __shared__ float bl[2 * D];
  for (int i = threadIdx.x; i < 2 * D * D; i += 256) Wl[i] = W[i];
  for (int i = threadIdx.x; i < 2 * D; i += 256) bl[i] = b[i];
  __syncthreads();
  const int wave = threadIdx.x >> 6;
  const int lane = threadIdx.x & 63;
  for (int e = blockIdx.x * 4 + wave; e < nEdges; e += gridDim.x * 4) {
    const int src = ei[e];
    const int dst = ei[nEdges + e];
    const int t = ea[e];
    const float xk = x[(size_t)src * D + lane];
    float acc = bl[t * D + lane];
    const float* Wt = &Wl[t * D * D];
#pragma unroll
    for (int k = 0; k < D; ++k)
      acc = fmaf(__shfl(xk, k, 64), Wt[k * D + lane], acc);
    float* p = out + (size_t)dst * D + lane;
    const float cur = *p;
    atomic_max_float(p, acc, cur);
  }
}

// ============================ launcher ============================

extern "C" void kernel_launch(void* const* d_in, const int* in_sizes, int n_in,
                              void* d_out, int out_size, void* d_ws, size_t ws_size,
                              hipStream_t stream) {
  const float* x = (const float*)d_in[0];
  const float* W = (const float*)d_in[1];
  const float* b = (const float*)d_in[2];
  const int* ei = (const int*)d_in[3];   // [2, E]: src row then dst row
  const int* ea = (const int*)d_in[4];   // [E]
  float* out = (float*)d_out;

  const int nNodes = in_sizes[0] / D;
  const int nEdges = in_sizes[4];
  const int n4out = (nNodes * D) / 4;
  const int nBins = (nNodes + NPB - 1) / NPB;

  // Workspace carve (256B-aligned regions).
  auto rup = [](size_t v) { return (v + 255) & ~(size_t)255; };
  const size_t xbB = (size_t)nNodes * D * sizeof(unsigned short);
  const size_t ybB = (size_t)2 * nNodes * D * sizeof(unsigned short);
  const size_t offXb = 0;
  const size_t offYb = rup(offXb + xbB);
  const size_t offCounts = rup(offYb + ybB);
  const size_t offOffs = rup(offCounts + (size_t)nBins * sizeof(int));
  const size_t offCur = rup(offOffs + (size_t)(nBins + 1) * sizeof(int));
  const size_t offBS = rup(offCur + (size_t)nBins * sizeof(int));
  const size_t offBinned = rup(offBS + (size_t)SCAN_BLOCKS * sizeof(int));
  const size_t need = offBinned + (size_t)nEdges * sizeof(unsigned);

  if (ws_size >= need && nNodes < (1 << 20)) {
    // ---- bf16 MFMA + coarse-bin LDS-reduction path ----
    char* ws = (char*)d_ws;
    unsigned short* xb = (unsigned short*)(ws + offXb);
    unsigned short* yb = (unsigned short*)(ws + offYb);
    int* counts = (int*)(ws + offCounts);
    int* offs = (int*)(ws + offOffs);
    int* cursors = (int*)(ws + offCur);
    int* blockSums = (int*)(ws + offBS);
    unsigned* binned = (unsigned*)(ws + offBinned);

    const int* srcRow = ei;
    const int* dstRow = ei + nEdges;
    const int nX4 = (nNodes * D) / 4;

    hipMemsetAsync(counts, 0, (size_t)nBins * sizeof(int), stream);
    k_cvt<<<2048, 256, 0, stream>>>((const float4*)x, (ushort2*)xb, nX4);
    k_hist_coarse<<<(nEdges + 255) / 256, 256, 0, stream>>>(dstRow, counts,
                                                            nEdges);
    k_scan_partial<<<SCAN_BLOCKS, 256, 0, stream>>>(counts, blockSums, nBins);
    k_scan_block<<<1, 256, 0, stream>>>(blockSums, offs, nBins, SCAN_BLOCKS);
    k_scan_write<<<SCAN_BLOCKS, 256, 0, stream>>>(counts, blockSums, offs,
                                                  cursors, nBins);
    k_binscatter<<<(nEdges + 255) / 256, 256, 0, stream>>>(
        srcRow, dstRow, ea, cursors, binned, nEdges);
    k_gemm<<<256, 256, 0, stream>>>(xb, W, b, yb, nNodes);
    k_reduce_bin<<<nBins, 256, 0, stream>>>(offs, binned, yb, out, nNodes);
  } else {
    // ---- fallback: direct edge compute with filtered atomics ----
    k_init_neginf<<<(n4out + 255) / 256, 256, 0, stream>>>((float4*)out, n4out);
    k_edge_direct<<<4096, 256, 0, stream>>>(x, W, b, ei, ea, out, nEdges);
    k_fixup<<<(n4out + 255) / 256, 256, 0, stream>>>((float4*)out, n4out);
  }
}

// Round 7
// 471.973 us; speedup vs baseline: 1.1037x; 1.1037x over previous
//
#include <hip/hip_runtime.h>
#include <math.h>

static constexpr int D = 64;
static constexpr int SCAN_BLOCKS = 256;
static constexpr int NB_CHUNK = 96;    // scatter chunk-blocks (run ~= 128B/line)
static constexpr int BIN_SHIFT = 8;    // 256 nodes per coarse bin
static constexpr int MAXBINS = 2048;   // LDS hist/cursor capacity (N <= 524288)

typedef __bf16 bf16x8 __attribute__((ext_vector_type(8)));
typedef float f32x4 __attribute__((ext_vector_type(4)));

// ============================ common helpers ============================

__device__ __forceinline__ unsigned short f2bf(float f) {  // RNE
  unsigned u = __float_as_uint(f);
  return (unsigned short)((u + 0x7fffu + ((u >> 16) & 1u)) >> 16);
}
__device__ __forceinline__ float bf2f(unsigned short h) {
  return __uint_as_float((unsigned)h << 16);
}

// Monotone float max via int/uint atomics (LDS or global).
__device__ __forceinline__ void lds_max_f32(float* p, float v) {
  if (v >= 0.0f)
    atomicMax(reinterpret_cast<int*>(p), __float_as_int(v));
  else
    atomicMin(reinterpret_cast<unsigned int*>(p), __float_as_uint(v));
}

__device__ __forceinline__ void atomic_max_float(float* p, float v, float cur) {
  if (!(v > cur)) return;
  if (v >= 0.0f)
    atomicMax(reinterpret_cast<int*>(p), __float_as_int(v));
  else
    atomicMin(reinterpret_cast<unsigned int*>(p), __float_as_uint(v));
}

__global__ void k_init_neginf(float4* __restrict__ out, int n4) {
  int i = blockIdx.x * blockDim.x + threadIdx.x;
  if (i < n4) {
    float4 v;
    v.x = v.y = v.z = v.w = -INFINITY;
    out[i] = v;
  }
}

// x fp32 -> bf16, 4 elems/thread.
__global__ __launch_bounds__(256) void k_cvt(const float4* __restrict__ x,
                                             ushort2* __restrict__ xb, int n4) {
  for (int i = blockIdx.x * blockDim.x + threadIdx.x; i < n4;
       i += gridDim.x * blockDim.x) {
    const float4 v = x[i];
    ushort2 a, b;
    a.x = f2bf(v.x); a.y = f2bf(v.y);
    b.x = f2bf(v.z); b.y = f2bf(v.w);
    xb[i * 2] = a;
    xb[i * 2 + 1] = b;
  }
}

// ============================ MFMA precompute ============================
// yb[t][n][o] = bf16( b[t][o] + sum_k x[n][k] * W[t][k][o] ), t in {0,1}
__global__ __launch_bounds__(256) void k_gemm(
    const unsigned short* __restrict__ xb, const float* __restrict__ W,
    const float* __restrict__ b, unsigned short* __restrict__ yb, int nN) {
  const int lane = threadIdx.x & 63;
  const int wid = (blockIdx.x << 2) + (threadIdx.x >> 6);
  const int nWaves = gridDim.x << 2;
  const int kgrp = (lane >> 4) << 3;  // 0,8,16,24
  const int nsub = lane & 15;

  bf16x8 Bf[8][2];
  float bias[8];
#pragma unroll
  for (int nt = 0; nt < 8; ++nt) {
    const int t = nt >> 2;
    const int n = ((nt & 3) << 4) + nsub;
#pragma unroll
    for (int ks = 0; ks < 2; ++ks) {
      bf16x8 f;
#pragma unroll
      for (int e = 0; e < 8; ++e) {
        const int k = (ks << 5) + kgrp + e;
        f[e] = (__bf16)W[t * 4096 + k * 64 + n];
      }
      Bf[nt][ks] = f;
    }
    bias[nt] = b[t * 64 + n];
  }

  const int nChunks = (nN + 15) >> 4;
  for (int c = wid; c < nChunks; c += nWaves) {
    const int base = c << 4;
    const int arow = min(base + nsub, nN - 1);
    const bf16x8 a0 =
        *reinterpret_cast<const bf16x8*>(xb + (size_t)arow * 64 + kgrp);
    const bf16x8 a1 =
        *reinterpret_cast<const bf16x8*>(xb + (size_t)arow * 64 + 32 + kgrp);
#pragma unroll
    for (int nt = 0; nt < 8; ++nt) {
      f32x4 acc = {bias[nt], bias[nt], bias[nt], bias[nt]};
      acc = __builtin_amdgcn_mfma_f32_16x16x32_bf16(a0, Bf[nt][0], acc, 0, 0, 0);
      acc = __builtin_amdgcn_mfma_f32_16x16x32_bf16(a1, Bf[nt][1], acc, 0, 0, 0);
      const int t = nt >> 2;
      const int o = ((nt & 3) << 4) + nsub;
      const int rbase = base + ((lane >> 4) << 2);
#pragma unroll
      for (int r = 0; r < 4; ++r) {
        const int node = rbase + r;
        if (node < nN) yb[((size_t)t * nN + node) * 64 + o] = f2bf(acc[r]);
      }
    }
  }
}

// ==================== deterministic two-level scatter ====================

// Phase 1: per-chunk-block LDS histogram of coarse bins (no global atomics).
// countsT layout is bin-major: countsT[bin * NB + blk].
__global__ __launch_bounds__(256) void k_lochist(const int* __restrict__ dst,
                                                 int* __restrict__ countsT,
                                                 int nE, int nBins, int chunk) {
  __shared__ int lh[MAXBINS];
  const int t = threadIdx.x;
  for (int i = t; i < nBins; i += 256) lh[i] = 0;
  __syncthreads();
  const int beg = blockIdx.x * chunk;
  const int end = min(beg + chunk, nE);
  for (int i = beg + t; i < end; i += 256) atomicAdd(&lh[dst[i] >> BIN_SHIFT], 1);
  __syncthreads();
  for (int i = t; i < nBins; i += 256)
    countsT[(size_t)i * gridDim.x + blockIdx.x] = lh[i];
}

// Phase 2: 3-phase scan over countsT (length nScan = nBins * NB).
__global__ __launch_bounds__(256) void k_scan_partial(
    const int* __restrict__ counts, int* __restrict__ blockSums, int nN) {
  __shared__ int red[256];
  const int t = threadIdx.x;
  const int seg = (nN + gridDim.x - 1) / gridDim.x;
  const int beg = blockIdx.x * seg;
  const int end = min(beg + seg, nN);
  int s = 0;
  for (int i = beg + t; i < end; i += 256) s += counts[i];
  red[t] = s;
  __syncthreads();
  for (int d = 128; d > 0; d >>= 1) {
    if (t < d) red[t] += red[t + d];
    __syncthreads();
  }
  if (t == 0) blockSums[blockIdx.x] = red[0];
}

__global__ __launch_bounds__(256) void k_scan_block(
    int* __restrict__ blockSums, int* __restrict__ offs, int nN, int nBlocks) {
  __shared__ int sh[256];
  const int t = threadIdx.x;
  const int v = (t < nBlocks) ? blockSums[t] : 0;
  sh[t] = v;
  __syncthreads();
  for (int d = 1; d < 256; d <<= 1) {
    const int o = (t >= d) ? sh[t - d] : 0;
    __syncthreads();
    sh[t] += o;
    __syncthreads();
  }
  if (t < nBlocks) blockSums[t] = sh[t] - v;
  if (t == 255) offs[nN] = sh[255];  // total == nE
}

__global__ __launch_bounds__(256) void k_scan_write(
    const int* __restrict__ counts, const int* __restrict__ blockSums,
    int* __restrict__ offs, int nN) {
  __shared__ int sh[256];
  const int t = threadIdx.x;
  const int seg = (nN + gridDim.x - 1) / gridDim.x;
  const int beg = blockIdx.x * seg;
  const int end = min(beg + seg, nN);
  int carry = blockSums[blockIdx.x];
  for (int base = beg; base < end; base += 256) {
    const int i = base + t;
    const int v = (i < end) ? counts[i] : 0;
    sh[t] = v;
    __syncthreads();
    for (int d = 1; d < 256; d <<= 1) {
      const int o = (t >= d) ? sh[t - d] : 0;
      __syncthreads();
      sh[t] += o;
      __syncthreads();
    }
    if (i < end) offs[i] = carry + sh[t] - v;
    carry += sh[255];
    __syncthreads();
  }
}

// Phase 3: scatter records using deterministic per-(bin,blk) starts; only
// LDS cursor atomics. Record: src(0-19) | type(20) | dstLow(21-28).
__global__ __launch_bounds__(256) void k_cscatter(
    const int* __restrict__ src, const int* __restrict__ dst,
    const int* __restrict__ ea, const int* __restrict__ offs,
    unsigned* __restrict__ rec, int nE, int nBins, int chunk) {
  __shared__ int cur[MAXBINS];
  const int t = threadIdx.x;
  for (int i = t; i < nBins; i += 256)
    cur[i] = offs[(size_t)i * gridDim.x + blockIdx.x];
  __syncthreads();
  const int beg = blockIdx.x * chunk;
  const int end = min(beg + chunk, nE);
  for (int i = beg + t; i < end; i += 256) {
    const int d = dst[i];
    const int pos = atomicAdd(&cur[d >> BIN_SHIFT], 1);
    rec[pos] = (unsigned)src[i] | ((unsigned)ea[i] << 20) |
               ((unsigned)(d & ((1 << BIN_SHIFT) - 1)) << 21);
  }
}

// ============================ reduction ============================
// One block per 64-node subgroup; scans parent 256-node bin's records
// (L2-hot broadcasts), gathers matching yb rows (wave-per-record, lane=ch),
// LDS [64][64] atomic max, coalesced out write with -inf -> 0 fused.
__global__ __launch_bounds__(256) void k_reduce_sub(
    const int* __restrict__ offs, const unsigned* __restrict__ rec,
    const unsigned short* __restrict__ yb, float* __restrict__ out, int nN) {
  __shared__ float acc[64 * 64];  // 16 KB
  const int t = threadIdx.x;
#pragma unroll
  for (int i = 0; i < 16; ++i) acc[t + i * 256] = -INFINITY;
  __syncthreads();

  const int sub = blockIdx.x;        // 64-node group
  const int bin = sub >> 2;          // parent 256-node bin
  const unsigned subid = sub & 3;
  const int beg = offs[bin * NB_CHUNK];
  const int end = offs[(bin + 1) * NB_CHUNK];
  const int w = t >> 6;
  const int lane = t & 63;

  for (int j = beg + w; j < end; j += 4) {
    const unsigned r = rec[j];
    const unsigned dl = (r >> 21) & 255u;
    if ((dl >> 6) == subid) {
      const float v =
          bf2f(yb[((size_t)((r >> 20) & 1u) * nN + (r & 0xFFFFFu)) * 64 + lane]);
      lds_max_f32(&acc[((dl & 63u) << 6) + lane], v);
    }
  }
  __syncthreads();

  const int nodeBase = sub << 6;
  for (int f = t; f < 64 * 16; f += 256) {  // one float4 per f
    const int node = nodeBase + (f >> 4);
    if (node < nN) {
      float4 v = *reinterpret_cast<const float4*>(&acc[f * 4]);
      if (v.x == -INFINITY) v.x = 0.0f;
      if (v.y == -INFINITY) v.y = 0.0f;
      if (v.z == -INFINITY) v.z = 0.0f;
      if (v.w == -INFINITY) v.w = 0.0f;
      *reinterpret_cast<float4*>(&out[(size_t)node * 64 + (f & 15) * 4]) = v;
    }
  }
}

// ============================ fallback kernels ============================

__global__ void k_fixup(float4* __restrict__ out, int n4) {
  int i = blockIdx.x * blockDim.x + threadIdx.x;
  if (i < n4) {
    float4 v = out[i];
    if (v.x == -INFINITY) v.x = 0.0f;
    if (v.y == -INFINITY) v.y = 0.0f;
    if (v.z == -INFINITY) v.z = 0.0f;
    if (v.w == -INFINITY) v.w = 0.0f;
    out[i] = v;
  }
}

__global__ __launch_bounds__(256) void k_edge_direct(
    const float* __restrict__ x, const float* __restrict__ W,
    const float* __restrict__ b, const int* __restrict__ ei,
    const int* __restrict__ ea, float* __restrict__ out, int nEdges) {
  __shared__ float Wl[2 * D * D];
  __shared__ float bl[2 * D];
  for (int i = threadIdx.x; i < 2 * D * D; i += 256) Wl[i] = W[i];
  for (int i = threadIdx.x; i < 2 * D; i += 256) bl[i] = b[i];
  __syncthreads();
  const int wave = threadIdx.x >> 6;
  const int lane = threadIdx.x & 63;
  for (int e = blockIdx.x * 4 + wave; e < nEdges; e += gridDim.x * 4) {
    const int src = ei[e];
    const int dst = ei[nEdges + e];
    const int t = ea[e];
    const float xk = x[(size_t)src * D + lane];
    float acc = bl[t * D + lane];
    const float* Wt = &Wl[t * D * D];
#pragma unroll
    for (int k = 0; k < D; ++k)
      acc = fmaf(__shfl(xk, k, 64), Wt[k * D + lane], acc);
    float* p = out + (size_t)dst * D + lane;
    const float cur = *p;
    atomic_max_float(p, acc, cur);
  }
}

// ============================ launcher ============================

extern "C" void kernel_launch(void* const* d_in, const int* in_sizes, int n_in,
                              void* d_out, int out_size, void* d_ws, size_t ws_size,
                              hipStream_t stream) {
  const float* x = (const float*)d_in[0];
  const float* W = (const float*)d_in[1];
  const float* b = (const float*)d_in[2];
  const int* ei = (const int*)d_in[3];   // [2, E]: src row then dst row
  const int* ea = (const int*)d_in[4];   // [E]
  float* out = (float*)d_out;

  const int nNodes = in_sizes[0] / D;
  const int nEdges = in_sizes[4];
  const int n4out = (nNodes * D) / 4;
  const int nBins = (nNodes + (1 << BIN_SHIFT) - 1) >> BIN_SHIFT;
  const int nScan = nBins * NB_CHUNK;
  const int nSub = (nNodes + 63) >> 6;
  const int chunk = (nEdges + NB_CHUNK - 1) / NB_CHUNK;

  // Workspace carve (256B-aligned regions).
  auto rup = [](size_t v) { return (v + 255) & ~(size_t)255; };
  const size_t xbB = (size_t)nNodes * D * sizeof(unsigned short);
  const size_t ybB = (size_t)2 * nNodes * D * sizeof(unsigned short);
  const size_t offXb = 0;
  const size_t offYb = rup(offXb + xbB);
  const size_t offCT = rup(offYb + ybB);
  const size_t offOffs = rup(offCT + (size_t)nScan * sizeof(int));
  const size_t offBS = rup(offOffs + (size_t)(nScan + 1) * sizeof(int));
  const size_t offRec = rup(offBS + (size_t)SCAN_BLOCKS * sizeof(int));
  const size_t need = offRec + (size_t)nEdges * sizeof(unsigned);

  if (ws_size >= need && nNodes < (1 << 20) && nBins <= MAXBINS) {
    // ---- bf16 MFMA + deterministic two-level scatter path ----
    char* ws = (char*)d_ws;
    unsigned short* xb = (unsigned short*)(ws + offXb);
    unsigned short* yb = (unsigned short*)(ws + offYb);
    int* countsT = (int*)(ws + offCT);
    int* offs = (int*)(ws + offOffs);
    int* blockSums = (int*)(ws + offBS);
    unsigned* rec = (unsigned*)(ws + offRec);

    const int* srcRow = ei;
    const int* dstRow = ei + nEdges;
    const int nX4 = (nNodes * D) / 4;

    k_lochist<<<NB_CHUNK, 256, 0, stream>>>(dstRow, countsT, nEdges, nBins, chunk);
    k_scan_partial<<<SCAN_BLOCKS, 256, 0, stream>>>(countsT, blockSums, nScan);
    k_scan_block<<<1, 256, 0, stream>>>(blockSums, offs, nScan, SCAN_BLOCKS);
    k_scan_write<<<SCAN_BLOCKS, 256, 0, stream>>>(countsT, blockSums, offs, nScan);
    k_cscatter<<<NB_CHUNK, 256, 0, stream>>>(srcRow, dstRow, ea, offs, rec,
                                             nEdges, nBins, chunk);
    k_cvt<<<2048, 256, 0, stream>>>((const float4*)x, (ushort2*)xb, nX4);
    k_gemm<<<256, 256, 0, stream>>>(xb, W, b, yb, nNodes);
    k_reduce_sub<<<nSub, 256, 0, stream>>>(offs, rec, yb, out, nNodes);
  } else {
    // ---- fallback: direct edge compute with filtered atomics ----
    k_init_neginf<<<(n4out + 255) / 256, 256, 0, stream>>>((float4*)out, n4out);
    k_edge_direct<<<4096, 256, 0, stream>>>(x, W, b, ei, ea, out, nEdges);
    k_fixup<<<(n4out + 255) / 256, 256, 0, stream>>>((float4*)out, n4out);
  }
}

// Round 8
// 214.116 us; speedup vs baseline: 2.4328x; 2.2043x over previous
//
#include <hip/hip_runtime.h>
#include <math.h>

static constexpr int D = 64;
static constexpr int SCAN_BLOCKS = 256;
static constexpr int NB_CHUNK = 96;    // scatter chunk-blocks
static constexpr int BIN_SHIFT = 6;    // 64 nodes per bin (exact reduce tiles)
static constexpr int MAXBINS = 2048;   // LDS hist/cursor capacity (N <= 131072)

typedef __bf16 bf16x8 __attribute__((ext_vector_type(8)));
typedef float f32x4 __attribute__((ext_vector_type(4)));

// ============================ common helpers ============================

__device__ __forceinline__ unsigned short f2bf(float f) {  // RNE
  unsigned u = __float_as_uint(f);
  return (unsigned short)((u + 0x7fffu + ((u >> 16) & 1u)) >> 16);
}
__device__ __forceinline__ float bf2f(unsigned short h) {
  return __uint_as_float((unsigned)h << 16);
}

// Monotone float max via int/uint atomics (LDS or global).
__device__ __forceinline__ void lds_max_f32(float* p, float v) {
  if (v >= 0.0f)
    atomicMax(reinterpret_cast<int*>(p), __float_as_int(v));
  else
    atomicMin(reinterpret_cast<unsigned int*>(p), __float_as_uint(v));
}

__device__ __forceinline__ void atomic_max_float(float* p, float v, float cur) {
  if (!(v > cur)) return;
  if (v >= 0.0f)
    atomicMax(reinterpret_cast<int*>(p), __float_as_int(v));
  else
    atomicMin(reinterpret_cast<unsigned int*>(p), __float_as_uint(v));
}

__global__ void k_init_neginf(float4* __restrict__ out, int n4) {
  int i = blockIdx.x * blockDim.x + threadIdx.x;
  if (i < n4) {
    float4 v;
    v.x = v.y = v.z = v.w = -INFINITY;
    out[i] = v;
  }
}

// x fp32 -> bf16, 4 elems/thread.
__global__ __launch_bounds__(256) void k_cvt(const float4* __restrict__ x,
                                             ushort2* __restrict__ xb, int n4) {
  for (int i = blockIdx.x * blockDim.x + threadIdx.x; i < n4;
       i += gridDim.x * blockDim.x) {
    const float4 v = x[i];
    ushort2 a, b;
    a.x = f2bf(v.x); a.y = f2bf(v.y);
    b.x = f2bf(v.z); b.y = f2bf(v.w);
    xb[i * 2] = a;
    xb[i * 2 + 1] = b;
  }
}

// ============================ MFMA precompute ============================
// yb[t][n][o] = bf16( b[t][o] + sum_k x[n][k] * W[t][k][o] ), t in {0,1}
__global__ __launch_bounds__(256) void k_gemm(
    const unsigned short* __restrict__ xb, const float* __restrict__ W,
    const float* __restrict__ b, unsigned short* __restrict__ yb, int nN) {
  const int lane = threadIdx.x & 63;
  const int wid = (blockIdx.x << 2) + (threadIdx.x >> 6);
  const int nWaves = gridDim.x << 2;
  const int kgrp = (lane >> 4) << 3;  // 0,8,16,24
  const int nsub = lane & 15;

  bf16x8 Bf[8][2];
  float bias[8];
#pragma unroll
  for (int nt = 0; nt < 8; ++nt) {
    const int t = nt >> 2;
    const int n = ((nt & 3) << 4) + nsub;
#pragma unroll
    for (int ks = 0; ks < 2; ++ks) {
      bf16x8 f;
#pragma unroll
      for (int e = 0; e < 8; ++e) {
        const int k = (ks << 5) + kgrp + e;
        f[e] = (__bf16)W[t * 4096 + k * 64 + n];
      }
      Bf[nt][ks] = f;
    }
    bias[nt] = b[t * 64 + n];
  }

  const int nChunks = (nN + 15) >> 4;
  for (int c = wid; c < nChunks; c += nWaves) {
    const int base = c << 4;
    const int arow = min(base + nsub, nN - 1);
    const bf16x8 a0 =
        *reinterpret_cast<const bf16x8*>(xb + (size_t)arow * 64 + kgrp);
    const bf16x8 a1 =
        *reinterpret_cast<const bf16x8*>(xb + (size_t)arow * 64 + 32 + kgrp);
#pragma unroll
    for (int nt = 0; nt < 8; ++nt) {
      f32x4 acc = {bias[nt], bias[nt], bias[nt], bias[nt]};
      acc = __builtin_amdgcn_mfma_f32_16x16x32_bf16(a0, Bf[nt][0], acc, 0, 0, 0);
      acc = __builtin_amdgcn_mfma_f32_16x16x32_bf16(a1, Bf[nt][1], acc, 0, 0, 0);
      const int t = nt >> 2;
      const int o = ((nt & 3) << 4) + nsub;
      const int rbase = base + ((lane >> 4) << 2);
#pragma unroll
      for (int r = 0; r < 4; ++r) {
        const int node = rbase + r;
        if (node < nN) yb[((size_t)t * nN + node) * 64 + o] = f2bf(acc[r]);
      }
    }
  }
}

// ==================== deterministic two-level scatter ====================

// Phase 1: per-chunk-block LDS histogram of bins (no global atomics).
// countsT layout is bin-major: countsT[bin * NB_CHUNK + blk].
__global__ __launch_bounds__(256) void k_lochist(const int* __restrict__ dst,
                                                 int* __restrict__ countsT,
                                                 int nE, int nBins, int chunk) {
  __shared__ int lh[MAXBINS];
  const int t = threadIdx.x;
  for (int i = t; i < nBins; i += 256) lh[i] = 0;
  __syncthreads();
  const int beg = blockIdx.x * chunk;
  const int end = min(beg + chunk, nE);
  for (int i = beg + t; i < end; i += 256) atomicAdd(&lh[dst[i] >> BIN_SHIFT], 1);
  __syncthreads();
  for (int i = t; i < nBins; i += 256)
    countsT[(size_t)i * gridDim.x + blockIdx.x] = lh[i];
}

// Phase 2: 3-phase scan over countsT (length nScan = nBins * NB_CHUNK).
__global__ __launch_bounds__(256) void k_scan_partial(
    const int* __restrict__ counts, int* __restrict__ blockSums, int nN) {
  __shared__ int red[256];
  const int t = threadIdx.x;
  const int seg = (nN + gridDim.x - 1) / gridDim.x;
  const int beg = blockIdx.x * seg;
  const int end = min(beg + seg, nN);
  int s = 0;
  for (int i = beg + t; i < end; i += 256) s += counts[i];
  red[t] = s;
  __syncthreads();
  for (int d = 128; d > 0; d >>= 1) {
    if (t < d) red[t] += red[t + d];
    __syncthreads();
  }
  if (t == 0) blockSums[blockIdx.x] = red[0];
}

__global__ __launch_bounds__(256) void k_scan_block(
    int* __restrict__ blockSums, int* __restrict__ offs, int nN, int nBlocks) {
  __shared__ int sh[256];
  const int t = threadIdx.x;
  const int v = (t < nBlocks) ? blockSums[t] : 0;
  sh[t] = v;
  __syncthreads();
  for (int d = 1; d < 256; d <<= 1) {
    const int o = (t >= d) ? sh[t - d] : 0;
    __syncthreads();
    sh[t] += o;
    __syncthreads();
  }
  if (t < nBlocks) blockSums[t] = sh[t] - v;
  if (t == 255) offs[nN] = sh[255];  // total == nE
}

__global__ __launch_bounds__(256) void k_scan_write(
    const int* __restrict__ counts, const int* __restrict__ blockSums,
    int* __restrict__ offs, int nN) {
  __shared__ int sh[256];
  const int t = threadIdx.x;
  const int seg = (nN + gridDim.x - 1) / gridDim.x;
  const int beg = blockIdx.x * seg;
  const int end = min(beg + seg, nN);
  int carry = blockSums[blockIdx.x];
  for (int base = beg; base < end; base += 256) {
    const int i = base + t;
    const int v = (i < end) ? counts[i] : 0;
    sh[t] = v;
    __syncthreads();
    for (int d = 1; d < 256; d <<= 1) {
      const int o = (t >= d) ? sh[t - d] : 0;
      __syncthreads();
      sh[t] += o;
      __syncthreads();
    }
    if (i < end) offs[i] = carry + sh[t] - v;
    carry += sh[255];
    __syncthreads();
  }
}

// Phase 3: scatter records using deterministic per-(bin,blk) starts; only
// LDS cursor atomics. Record: src(0-19) | type(20) | dstLow(21-26).
__global__ __launch_bounds__(256) void k_cscatter(
    const int* __restrict__ src, const int* __restrict__ dst,
    const int* __restrict__ ea, const int* __restrict__ offs,
    unsigned* __restrict__ rec, int nE, int nBins, int chunk) {
  __shared__ int cur[MAXBINS];
  const int t = threadIdx.x;
  for (int i = t; i < nBins; i += 256)
    cur[i] = offs[(size_t)i * gridDim.x + blockIdx.x];
  __syncthreads();
  const int beg = blockIdx.x * chunk;
  const int end = min(beg + chunk, nE);
  for (int i = beg + t; i < end; i += 256) {
    const int d = dst[i];
    const int pos = atomicAdd(&cur[d >> BIN_SHIFT], 1);
    rec[pos] = (unsigned)src[i] | ((unsigned)ea[i] << 20) |
               ((unsigned)(d & ((1 << BIN_SHIFT) - 1)) << 21);
  }
}

// ============================ reduction ============================
// One block per 64-node bin with an EXACT record range (no redundancy, no
// filter). 4 waves split the range; 4-wide unroll keeps 4 independent
// 128B y-gathers in flight. LDS [64][64] atomic max (lane%32 banks, 2-way
// alias = free), then coalesced out write with -inf -> 0 fused.
__global__ __launch_bounds__(256) void k_reduce_bin(
    const int* __restrict__ offs, const unsigned* __restrict__ rec,
    const unsigned short* __restrict__ yb, float* __restrict__ out, int nN) {
  __shared__ float acc[64 * 64];  // 16 KB
  const int t = threadIdx.x;
#pragma unroll
  for (int i = 0; i < 16; ++i) acc[t + i * 256] = -INFINITY;
  __syncthreads();

  const int bin = blockIdx.x;
  const int beg = offs[bin * NB_CHUNK];
  const int cnt = offs[(bin + 1) * NB_CHUNK] - beg;
  const int w = t >> 6;
  const int lane = t & 63;
  const int myBeg = beg + ((cnt * w) >> 2);
  const int myEnd = beg + ((cnt * (w + 1)) >> 2);

  int j = myBeg;
  for (; j + 3 < myEnd; j += 4) {
    const unsigned r0 = rec[j];
    const unsigned r1 = rec[j + 1];
    const unsigned r2 = rec[j + 2];
    const unsigned r3 = rec[j + 3];
    const float v0 = bf2f(yb[((size_t)((r0 >> 20) & 1u) * nN + (r0 & 0xFFFFFu)) * 64 + lane]);
    const float v1 = bf2f(yb[((size_t)((r1 >> 20) & 1u) * nN + (r1 & 0xFFFFFu)) * 64 + lane]);
    const float v2 = bf2f(yb[((size_t)((r2 >> 20) & 1u) * nN + (r2 & 0xFFFFFu)) * 64 + lane]);
    const float v3 = bf2f(yb[((size_t)((r3 >> 20) & 1u) * nN + (r3 & 0xFFFFFu)) * 64 + lane]);
    lds_max_f32(&acc[(((r0 >> 21) & 63u) << 6) + lane], v0);
    lds_max_f32(&acc[(((r1 >> 21) & 63u) << 6) + lane], v1);
    lds_max_f32(&acc[(((r2 >> 21) & 63u) << 6) + lane], v2);
    lds_max_f32(&acc[(((r3 >> 21) & 63u) << 6) + lane], v3);
  }
  for (; j < myEnd; ++j) {
    const unsigned r0 = rec[j];
    const float v0 = bf2f(yb[((size_t)((r0 >> 20) & 1u) * nN + (r0 & 0xFFFFFu)) * 64 + lane]);
    lds_max_f32(&acc[(((r0 >> 21) & 63u) << 6) + lane], v0);
  }
  __syncthreads();

  const int nodeBase = bin << 6;
  for (int f = t; f < 64 * 16; f += 256) {  // one float4 per f
    const int node = nodeBase + (f >> 4);
    if (node < nN) {
      float4 v = *reinterpret_cast<const float4*>(&acc[f * 4]);
      if (v.x == -INFINITY) v.x = 0.0f;
      if (v.y == -INFINITY) v.y = 0.0f;
      if (v.z == -INFINITY) v.z = 0.0f;
      if (v.w == -INFINITY) v.w = 0.0f;
      *reinterpret_cast<float4*>(&out[(size_t)node * 64 + (f & 15) * 4]) = v;
    }
  }
}

// ============================ fallback kernels ============================

__global__ void k_fixup(float4* __restrict__ out, int n4) {
  int i = blockIdx.x * blockDim.x + threadIdx.x;
  if (i < n4) {
    float4 v = out[i];
    if (v.x == -INFINITY) v.x = 0.0f;
    if (v.y == -INFINITY) v.y = 0.0f;
    if (v.z == -INFINITY) v.z = 0.0f;
    if (v.w == -INFINITY) v.w = 0.0f;
    out[i] = v;
  }
}

__global__ __launch_bounds__(256) void k_edge_direct(
    const float* __restrict__ x, const float* __restrict__ W,
    const float* __restrict__ b, const int* __restrict__ ei,
    const int* __restrict__ ea, float* __restrict__ out, int nEdges) {
  __shared__ float Wl[2 * D * D];
  __shared__ float bl[2 * D];
  for (int i = threadIdx.x; i < 2 * D * D; i += 256) Wl[i] = W[i];
  for (int i = threadIdx.x; i < 2 * D; i += 256) bl[i] = b[i];
  __syncthreads();
  const int wave = threadIdx.x >> 6;
  const int lane = threadIdx.x & 63;
  for (int e = blockIdx.x * 4 + wave; e < nEdges; e += gridDim.x * 4) {
    const int src = ei[e];
    const int dst = ei[nEdges + e];
    const int t = ea[e];
    const float xk = x[(size_t)src * D + lane];
    float acc = bl[t * D + lane];
    const float* Wt = &Wl[t * D * D];
#pragma unroll
    for (int k = 0; k < D; ++k)
      acc = fmaf(__shfl(xk, k, 64), Wt[k * D + lane], acc);
    float* p = out + (size_t)dst * D + lane;
    const float cur = *p;
    atomic_max_float(p, acc, cur);
  }
}

// ============================ launcher ============================

extern "C" void kernel_launch(void* const* d_in, const int* in_sizes, int n_in,
                              void* d_out, int out_size, void* d_ws, size_t ws_size,
                              hipStream_t stream) {
  const float* x = (const float*)d_in[0];
  const float* W = (const float*)d_in[1];
  const float* b = (const float*)d_in[2];
  const int* ei = (const int*)d_in[3];   // [2, E]: src row then dst row
  const int* ea = (const int*)d_in[4];   // [E]
  float* out = (float*)d_out;

  const int nNodes = in_sizes[0] / D;
  const int nEdges = in_sizes[4];
  const int n4out = (nNodes * D) / 4;
  const int nBins = (nNodes + (1 << BIN_SHIFT) - 1) >> BIN_SHIFT;
  const int nScan = nBins * NB_CHUNK;
  const int chunk = (nEdges + NB_CHUNK - 1) / NB_CHUNK;

  // Workspace carve (256B-aligned regions).
  auto rup = [](size_t v) { return (v + 255) & ~(size_t)255; };
  const size_t xbB = (size_t)nNodes * D * sizeof(unsigned short);
  const size_t ybB = (size_t)2 * nNodes * D * sizeof(unsigned short);
  const size_t offXb = 0;
  const size_t offYb = rup(offXb + xbB);
  const size_t offCT = rup(offYb + ybB);
  const size_t offOffs = rup(offCT + (size_t)nScan * sizeof(int));
  const size_t offBS = rup(offOffs + (size_t)(nScan + 1) * sizeof(int));
  const size_t offRec = rup(offBS + (size_t)SCAN_BLOCKS * sizeof(int));
  const size_t need = offRec + (size_t)nEdges * sizeof(unsigned);

  if (ws_size >= need && nNodes < (1 << 20) && nBins <= MAXBINS) {
    // ---- bf16 MFMA + deterministic two-level scatter path ----
    char* ws = (char*)d_ws;
    unsigned short* xb = (unsigned short*)(ws + offXb);
    unsigned short* yb = (unsigned short*)(ws + offYb);
    int* countsT = (int*)(ws + offCT);
    int* offs = (int*)(ws + offOffs);
    int* blockSums = (int*)(ws + offBS);
    unsigned* rec = (unsigned*)(ws + offRec);

    const int* srcRow = ei;
    const int* dstRow = ei + nEdges;
    const int nX4 = (nNodes * D) / 4;

    k_lochist<<<NB_CHUNK, 256, 0, stream>>>(dstRow, countsT, nEdges, nBins, chunk);
    k_scan_partial<<<SCAN_BLOCKS, 256, 0, stream>>>(countsT, blockSums, nScan);
    k_scan_block<<<1, 256, 0, stream>>>(blockSums, offs, nScan, SCAN_BLOCKS);
    k_scan_write<<<SCAN_BLOCKS, 256, 0, stream>>>(countsT, blockSums, offs, nScan);
    k_cscatter<<<NB_CHUNK, 256, 0, stream>>>(srcRow, dstRow, ea, offs, rec,
                                             nEdges, nBins, chunk);
    k_cvt<<<2048, 256, 0, stream>>>((const float4*)x, (ushort2*)xb, nX4);
    k_gemm<<<256, 256, 0, stream>>>(xb, W, b, yb, nNodes);
    k_reduce_bin<<<nBins, 256, 0, stream>>>(offs, rec, yb, out, nNodes);
  } else {
    // ---- fallback: direct edge compute with filtered atomics ----
    k_init_neginf<<<(n4out + 255) / 256, 256, 0, stream>>>((float4*)out, n4out);
    k_edge_direct<<<4096, 256, 0, stream>>>(x, W, b, ei, ea, out, nEdges);
    k_fixup<<<(n4out + 255) / 256, 256, 0, stream>>>((float4*)out, n4out);
  }
}

// Round 10
// 190.558 us; speedup vs baseline: 2.7336x; 1.1236x over previous
//
#include <hip/hip_runtime.h>
#include <math.h>

static constexpr int D = 64;
static constexpr int SCAN_BLOCKS = 256;
static constexpr int NB_CHUNK = 96;    // scatter chunk-blocks (run ~32B)
static constexpr int BIN_SHIFT = 6;    // 64 nodes per bin (exact reduce tiles)
static constexpr int MAXBINS = 2048;   // LDS hist/cursor capacity (N <= 131072)

typedef __bf16 bf16x8 __attribute__((ext_vector_type(8)));
typedef float f32x4 __attribute__((ext_vector_type(4)));

// ============================ common helpers ============================

__device__ __forceinline__ unsigned short f2bf(float f) {  // RNE
  unsigned u = __float_as_uint(f);
  return (unsigned short)((u + 0x7fffu + ((u >> 16) & 1u)) >> 16);
}
__device__ __forceinline__ float bf2f(unsigned short h) {
  return __uint_as_float((unsigned)h << 16);
}

// Monotone float max via int/uint atomics (LDS or global).
__device__ __forceinline__ void lds_max_f32(float* p, float v) {
  if (v >= 0.0f)
    atomicMax(reinterpret_cast<int*>(p), __float_as_int(v));
  else
    atomicMin(reinterpret_cast<unsigned int*>(p), __float_as_uint(v));
}

__device__ __forceinline__ void atomic_max_float(float* p, float v, float cur) {
  if (!(v > cur)) return;
  if (v >= 0.0f)
    atomicMax(reinterpret_cast<int*>(p), __float_as_int(v));
  else
    atomicMin(reinterpret_cast<unsigned int*>(p), __float_as_uint(v));
}

__global__ void k_init_neginf(float4* __restrict__ out, int n4) {
  int i = blockIdx.x * blockDim.x + threadIdx.x;
  if (i < n4) {
    float4 v;
    v.x = v.y = v.z = v.w = -INFINITY;
    out[i] = v;
  }
}

// ============================ MFMA precompute ============================
// yb[t][n][o] = bf16( b[t][o] + sum_k x[n][k] * W[t][k][o] ), t in {0,1}
// cvt fused: reads x as f32, converts the A-fragment in-register.
__global__ __launch_bounds__(256) void k_gemm(
    const float* __restrict__ x, const float* __restrict__ W,
    const float* __restrict__ b, unsigned short* __restrict__ yb, int nN) {
  const int lane = threadIdx.x & 63;
  const int wid = (blockIdx.x << 2) + (threadIdx.x >> 6);
  const int nWaves = gridDim.x << 2;
  const int kgrp = (lane >> 4) << 3;  // 0,8,16,24
  const int nsub = lane & 15;

  bf16x8 Bf[8][2];
  float bias[8];
#pragma unroll
  for (int nt = 0; nt < 8; ++nt) {
    const int t = nt >> 2;
    const int n = ((nt & 3) << 4) + nsub;
#pragma unroll
    for (int ks = 0; ks < 2; ++ks) {
      bf16x8 f;
#pragma unroll
      for (int e = 0; e < 8; ++e) {
        const int k = (ks << 5) + kgrp + e;
        f[e] = (__bf16)W[t * 4096 + k * 64 + n];
      }
      Bf[nt][ks] = f;
    }
    bias[nt] = b[t * 64 + n];
  }

  const int nChunks = (nN + 15) >> 4;
  for (int c = wid; c < nChunks; c += nWaves) {
    const int base = c << 4;
    const int arow = min(base + nsub, nN - 1);
    const float4 xa0 = *reinterpret_cast<const float4*>(x + (size_t)arow * 64 + kgrp);
    const float4 xa1 = *reinterpret_cast<const float4*>(x + (size_t)arow * 64 + kgrp + 4);
    const float4 xb0 = *reinterpret_cast<const float4*>(x + (size_t)arow * 64 + 32 + kgrp);
    const float4 xb1 = *reinterpret_cast<const float4*>(x + (size_t)arow * 64 + 36 + kgrp);
    bf16x8 a0, a1;
    a0[0] = (__bf16)xa0.x; a0[1] = (__bf16)xa0.y; a0[2] = (__bf16)xa0.z; a0[3] = (__bf16)xa0.w;
    a0[4] = (__bf16)xa1.x; a0[5] = (__bf16)xa1.y; a0[6] = (__bf16)xa1.z; a0[7] = (__bf16)xa1.w;
    a1[0] = (__bf16)xb0.x; a1[1] = (__bf16)xb0.y; a1[2] = (__bf16)xb0.z; a1[3] = (__bf16)xb0.w;
    a1[4] = (__bf16)xb1.x; a1[5] = (__bf16)xb1.y; a1[6] = (__bf16)xb1.z; a1[7] = (__bf16)xb1.w;
#pragma unroll
    for (int nt = 0; nt < 8; ++nt) {
      f32x4 acc = {bias[nt], bias[nt], bias[nt], bias[nt]};
      acc = __builtin_amdgcn_mfma_f32_16x16x32_bf16(a0, Bf[nt][0], acc, 0, 0, 0);
      acc = __builtin_amdgcn_mfma_f32_16x16x32_bf16(a1, Bf[nt][1], acc, 0, 0, 0);
      const int t = nt >> 2;
      const int o = ((nt & 3) << 4) + nsub;
      const int rbase = base + ((lane >> 4) << 2);
#pragma unroll
      for (int r = 0; r < 4; ++r) {
        const int node = rbase + r;
        if (node < nN) yb[((size_t)t * nN + node) * 64 + o] = f2bf(acc[r]);
      }
    }
  }
}

// ==================== deterministic two-level scatter ====================

// Phase 1: per-chunk-block LDS histogram of bins (no global atomics).
// countsT layout is bin-major: countsT[bin * NB_CHUNK + blk].
// 1024 threads: 16 waves/CU for latency hiding (96-block grid).
__global__ __launch_bounds__(1024) void k_lochist(const int* __restrict__ dst,
                                                  int* __restrict__ countsT,
                                                  int nE, int nBins, int chunk) {
  __shared__ int lh[MAXBINS];
  const int t = threadIdx.x;
  for (int i = t; i < nBins; i += 1024) lh[i] = 0;
  __syncthreads();
  const int beg = blockIdx.x * chunk;
  const int end = min(beg + chunk, nE);
  for (int i = beg + t; i < end; i += 1024) atomicAdd(&lh[dst[i] >> BIN_SHIFT], 1);
  __syncthreads();
  for (int i = t; i < nBins; i += 1024)
    countsT[(size_t)i * gridDim.x + blockIdx.x] = lh[i];
}

// Phase 2: 3-phase scan over countsT (length nScan = nBins * NB_CHUNK).
__global__ __launch_bounds__(256) void k_scan_partial(
    const int* __restrict__ counts, int* __restrict__ blockSums, int nN) {
  __shared__ int red[256];
  const int t = threadIdx.x;
  const int seg = (nN + gridDim.x - 1) / gridDim.x;
  const int beg = blockIdx.x * seg;
  const int end = min(beg + seg, nN);
  int s = 0;
  for (int i = beg + t; i < end; i += 256) s += counts[i];
  red[t] = s;
  __syncthreads();
  for (int d = 128; d > 0; d >>= 1) {
    if (t < d) red[t] += red[t + d];
    __syncthreads();
  }
  if (t == 0) blockSums[blockIdx.x] = red[0];
}

__global__ __launch_bounds__(256) void k_scan_block(
    int* __restrict__ blockSums, int* __restrict__ offs, int nN, int nBlocks) {
  __shared__ int sh[256];
  const int t = threadIdx.x;
  const int v = (t < nBlocks) ? blockSums[t] : 0;
  sh[t] = v;
  __syncthreads();
  for (int d = 1; d < 256; d <<= 1) {
    const int o = (t >= d) ? sh[t - d] : 0;
    __syncthreads();
    sh[t] += o;
    __syncthreads();
  }
  if (t < nBlocks) blockSums[t] = sh[t] - v;
  if (t == 255) offs[nN] = sh[255];  // total == nE
}

__global__ __launch_bounds__(256) void k_scan_write(
    const int* __restrict__ counts, const int* __restrict__ blockSums,
    int* __restrict__ offs, int nN) {
  __shared__ int sh[256];
  const int t = threadIdx.x;
  const int seg = (nN + gridDim.x - 1) / gridDim.x;
  const int beg = blockIdx.x * seg;
  const int end = min(beg + seg, nN);
  int carry = blockSums[blockIdx.x];
  for (int base = beg; base < end; base += 256) {
    const int i = base + t;
    const int v = (i < end) ? counts[i] : 0;
    sh[t] = v;
    __syncthreads();
    for (int d = 1; d < 256; d <<= 1) {
      const int o = (t >= d) ? sh[t - d] : 0;
      __syncthreads();
      sh[t] += o;
      __syncthreads();
    }
    if (i < end) offs[i] = carry + sh[t] - v;
    carry += sh[255];
    __syncthreads();
  }
}

// Phase 3: scatter records using deterministic per-(bin,blk) starts; only
// LDS cursor atomics. Record: src(0-19) | type(20) | dstLow(21-26).
__global__ __launch_bounds__(1024) void k_cscatter(
    const int* __restrict__ src, const int* __restrict__ dst,
    const int* __restrict__ ea, const int* __restrict__ offs,
    unsigned* __restrict__ rec, int nE, int nBins, int chunk) {
  __shared__ int cur[MAXBINS];
  const int t = threadIdx.x;
  for (int i = t; i < nBins; i += 1024)
    cur[i] = offs[(size_t)i * gridDim.x + blockIdx.x];
  __syncthreads();
  const int beg = blockIdx.x * chunk;
  const int end = min(beg + chunk, nE);
  for (int i = beg + t; i < end; i += 1024) {
    const int d = dst[i];
    const int pos = atomicAdd(&cur[d >> BIN_SHIFT], 1);
    rec[pos] = (unsigned)src[i] | ((unsigned)ea[i] << 20) |
               ((unsigned)(d & ((1 << BIN_SHIFT) - 1)) << 21);
  }
}

// ============================ reduction ============================
// One block per 64-node bin with an EXACT record range. 4 waves split the
// range; 8-wide unroll keeps 8 independent 128B y-gathers in flight per
// wave. 32-bit index math (y < 2^25 elements). LDS [64][64] atomic max,
// coalesced out write with -inf -> 0 fused.
__global__ __launch_bounds__(256) void k_reduce_bin(
    const int* __restrict__ offs, const unsigned* __restrict__ rec,
    const unsigned short* __restrict__ yb, float* __restrict__ out, int nN) {
  __shared__ float acc[64 * 64];  // 16 KB
  const int t = threadIdx.x;
#pragma unroll
  for (int i = 0; i < 16; ++i) acc[t + i * 256] = -INFINITY;
  __syncthreads();

  const int bin = blockIdx.x;
  const int beg = offs[bin * NB_CHUNK];
  const int cnt = offs[(bin + 1) * NB_CHUNK] - beg;
  const int w = t >> 6;
  const unsigned lane = t & 63;
  const unsigned nNu = (unsigned)nN;
  const int myBeg = beg + ((cnt * w) >> 2);
  const int myEnd = beg + ((cnt * (w + 1)) >> 2);

  int j = myBeg;
  for (; j + 7 < myEnd; j += 8) {
    unsigned r[8];
    float v[8];
#pragma unroll
    for (int q = 0; q < 8; ++q) r[q] = rec[j + q];
#pragma unroll
    for (int q = 0; q < 8; ++q)
      v[q] = bf2f(yb[((((r[q] >> 20) & 1u) * nNu + (r[q] & 0xFFFFFu)) << 6) + lane]);
#pragma unroll
    for (int q = 0; q < 8; ++q)
      lds_max_f32(&acc[(((r[q] >> 21) & 63u) << 6) + lane], v[q]);
  }
  for (; j + 3 < myEnd; j += 4) {
    unsigned r[4];
    float v[4];
#pragma unroll
    for (int q = 0; q < 4; ++q) r[q] = rec[j + q];
#pragma unroll
    for (int q = 0; q < 4; ++q)
      v[q] = bf2f(yb[((((r[q] >> 20) & 1u) * nNu + (r[q] & 0xFFFFFu)) << 6) + lane]);
#pragma unroll
    for (int q = 0; q < 4; ++q)
      lds_max_f32(&acc[(((r[q] >> 21) & 63u) << 6) + lane], v[q]);
  }
  for (; j < myEnd; ++j) {
    const unsigned r0 = rec[j];
    const float v0 = bf2f(yb[((((r0 >> 20) & 1u) * nNu + (r0 & 0xFFFFFu)) << 6) + lane]);
    lds_max_f32(&acc[(((r0 >> 21) & 63u) << 6) + lane], v0);
  }
  __syncthreads();

  const int nodeBase = bin << 6;
  for (int f = t; f < 64 * 16; f += 256) {  // one float4 per f
    const int node = nodeBase + (f >> 4);
    if (node < nN) {
      float4 v = *reinterpret_cast<const float4*>(&acc[f * 4]);
      if (v.x == -INFINITY) v.x = 0.0f;
      if (v.y == -INFINITY) v.y = 0.0f;
      if (v.z == -INFINITY) v.z = 0.0f;
      if (v.w == -INFINITY) v.w = 0.0f;
      *reinterpret_cast<float4*>(&out[(size_t)node * 64 + (f & 15) * 4]) = v;
    }
  }
}

// ============================ fallback kernels ============================

__global__ void k_fixup(float4* __restrict__ out, int n4) {
  int i = blockIdx.x * blockDim.x + threadIdx.x;
  if (i < n4) {
    float4 v = out[i];
    if (v.x == -INFINITY) v.x = 0.0f;
    if (v.y == -INFINITY) v.y = 0.0f;
    if (v.z == -INFINITY) v.z = 0.0f;
    if (v.w == -INFINITY) v.w = 0.0f;
    out[i] = v;
  }
}

__global__ __launch_bounds__(256) void k_edge_direct(
    const float* __restrict__ x, const float* __restrict__ W,
    const float* __restrict__ b, const int* __restrict__ ei,
    const int* __restrict__ ea, float* __restrict__ out, int nEdges) {
  __shared__ float Wl[2 * D * D];
  __shared__ float bl[2 * D];
  for (int i = threadIdx.x; i < 2 * D * D; i += 256) Wl[i] = W[i];
  for (int i = threadIdx.x; i < 2 * D; i += 256) bl[i] = b[i];
  __syncthreads();
  const int wave = threadIdx.x >> 6;
  const int lane = threadIdx.x & 63;
  for (int e = blockIdx.x * 4 + wave; e < nEdges; e += gridDim.x * 4) {
    const int src = ei[e];
    const int dst = ei[nEdges + e];
    const int t = ea[e];
    const float xk = x[(size_t)src * D + lane];
    float acc = bl[t * D + lane];
    const float* Wt = &Wl[t * D * D];
#pragma unroll
    for (int k = 0; k < D; ++k)
      acc = fmaf(__shfl(xk, k, 64), Wt[k * D + lane], acc);
    float* p = out + (size_t)dst * D + lane;
    const float cur = *p;
    atomic_max_float(p, acc, cur);
  }
}

// ============================ launcher ============================

extern "C" void kernel_launch(void* const* d_in, const int* in_sizes, int n_in,
                              void* d_out, int out_size, void* d_ws, size_t ws_size,
                              hipStream_t stream) {
  const float* x = (const float*)d_in[0];
  const float* W = (const float*)d_in[1];
  const float* b = (const float*)d_in[2];
  const int* ei = (const int*)d_in[3];   // [2, E]: src row then dst row
  const int* ea = (const int*)d_in[4];   // [E]
  float* out = (float*)d_out;

  const int nNodes = in_sizes[0] / D;
  const int nEdges = in_sizes[4];
  const int n4out = (nNodes * D) / 4;
  const int nBins = (nNodes + (1 << BIN_SHIFT) - 1) >> BIN_SHIFT;
  const int nScan = nBins * NB_CHUNK;
  const int chunk = (nEdges + NB_CHUNK - 1) / NB_CHUNK;

  // Workspace carve (256B-aligned regions).
  auto rup = [](size_t v) { return (v + 255) & ~(size_t)255; };
  const size_t ybB = (size_t)2 * nNodes * D * sizeof(unsigned short);
  const size_t offYb = 0;
  const size_t offCT = rup(offYb + ybB);
  const size_t offOffs = rup(offCT + (size_t)nScan * sizeof(int));
  const size_t offBS = rup(offOffs + (size_t)(nScan + 1) * sizeof(int));
  const size_t offRec = rup(offBS + (size_t)SCAN_BLOCKS * sizeof(int));
  const size_t need = offRec + (size_t)nEdges * sizeof(unsigned);

  if (ws_size >= need && nNodes < (1 << 20) && nBins <= MAXBINS) {
    // ---- bf16 MFMA + deterministic two-level scatter path ----
    char* ws = (char*)d_ws;
    unsigned short* yb = (unsigned short*)(ws + offYb);
    int* countsT = (int*)(ws + offCT);
    int* offs = (int*)(ws + offOffs);
    int* blockSums = (int*)(ws + offBS);
    unsigned* rec = (unsigned*)(ws + offRec);

    const int* srcRow = ei;
    const int* dstRow = ei + nEdges;

    k_lochist<<<NB_CHUNK, 1024, 0, stream>>>(dstRow, countsT, nEdges, nBins, chunk);
    k_scan_partial<<<SCAN_BLOCKS, 256, 0, stream>>>(countsT, blockSums, nScan);
    k_scan_block<<<1, 256, 0, stream>>>(blockSums, offs, nScan, SCAN_BLOCKS);
    k_scan_write<<<SCAN_BLOCKS, 256, 0, stream>>>(countsT, blockSums, offs, nScan);
    k_cscatter<<<NB_CHUNK, 1024, 0, stream>>>(srcRow, dstRow, ea, offs, rec,
                                              nEdges, nBins, chunk);
    k_gemm<<<512, 256, 0, stream>>>(x, W, b, yb, nNodes);
    k_reduce_bin<<<nBins, 256, 0, stream>>>(offs, rec, yb, out, nNodes);
  } else {
    // ---- fallback: direct edge compute with filtered atomics ----
    k_init_neginf<<<(n4out + 255) / 256, 256, 0, stream>>>((float4*)out, n4out);
    k_edge_direct<<<4096, 256, 0, stream>>>(x, W, b, ei, ea, out, nEdges);
    k_fixup<<<(n4out + 255) / 256, 256, 0, stream>>>((float4*)out, n4out);
  }
}

// Round 11
// 167.067 us; speedup vs baseline: 3.1180x; 1.1406x over previous
//
#include <hip/hip_runtime.h>
#include <math.h>

static constexpr int D = 64;
static constexpr int SCAN_BLOCKS = 256;
static constexpr int NB_CHUNK = 96;    // scatter chunk-blocks (run ~32B)
static constexpr int BIN_SHIFT = 6;    // 64 nodes per bin (exact reduce tiles)
static constexpr int MAXBINS = 2048;   // LDS hist/cursor capacity (N <= 131072)

typedef __bf16 bf16x8 __attribute__((ext_vector_type(8)));
typedef float f32x4 __attribute__((ext_vector_type(4)));

// ============================ common helpers ============================

__device__ __forceinline__ unsigned short f2bf(float f) {  // RNE
  unsigned u = __float_as_uint(f);
  return (unsigned short)((u + 0x7fffu + ((u >> 16) & 1u)) >> 16);
}

// Order-preserving bf16 encoding: enc(u) compares as unsigned exactly like
// the underlying float. enc = u ^ (0x8000 | (u>>15 ? 0xFFFF : 0)).
__device__ __forceinline__ unsigned short bf_enc(unsigned short u) {
  const unsigned short s = (unsigned short)(-(int)(u >> 15));  // 0xFFFF if neg
  return (unsigned short)(u ^ (s | 0x8000u));
}
__device__ __forceinline__ float bf_dec_to_f32(unsigned enc32) {
  // enc32 = enc16 << 16 (or 0 = untouched -> 0.0f)
  if (enc32 == 0u) return 0.0f;
  unsigned short enc = (unsigned short)(enc32 >> 16);
  unsigned short u = (enc & 0x8000u) ? (unsigned short)(enc ^ 0x8000u)
                                     : (unsigned short)(~enc);
  return __uint_as_float((unsigned)u << 16);
}

__device__ __forceinline__ void atomic_max_float(float* p, float v, float cur) {
  if (!(v > cur)) return;
  if (v >= 0.0f)
    atomicMax(reinterpret_cast<int*>(p), __float_as_int(v));
  else
    atomicMin(reinterpret_cast<unsigned int*>(p), __float_as_uint(v));
}

__global__ void k_init_neginf(float4* __restrict__ out, int n4) {
  int i = blockIdx.x * blockDim.x + threadIdx.x;
  if (i < n4) {
    float4 v;
    v.x = v.y = v.z = v.w = -INFINITY;
    out[i] = v;
  }
}

// ============================ MFMA precompute ============================
// yb[t][n][o] = ENC16( bf16( b[t][o] + sum_k x[n][k]*W[t][k][o] ) ), t in {0,1}
// cvt fused (reads f32 x); output stored in order-preserving encoding.
__global__ __launch_bounds__(256) void k_gemm(
    const float* __restrict__ x, const float* __restrict__ W,
    const float* __restrict__ b, unsigned short* __restrict__ yb, int nN) {
  const int lane = threadIdx.x & 63;
  const int wid = (blockIdx.x << 2) + (threadIdx.x >> 6);
  const int nWaves = gridDim.x << 2;
  const int kgrp = (lane >> 4) << 3;  // 0,8,16,24
  const int nsub = lane & 15;

  bf16x8 Bf[8][2];
  float bias[8];
#pragma unroll
  for (int nt = 0; nt < 8; ++nt) {
    const int t = nt >> 2;
    const int n = ((nt & 3) << 4) + nsub;
#pragma unroll
    for (int ks = 0; ks < 2; ++ks) {
      bf16x8 f;
#pragma unroll
      for (int e = 0; e < 8; ++e) {
        const int k = (ks << 5) + kgrp + e;
        f[e] = (__bf16)W[t * 4096 + k * 64 + n];
      }
      Bf[nt][ks] = f;
    }
    bias[nt] = b[t * 64 + n];
  }

  const int nChunks = (nN + 15) >> 4;
  for (int c = wid; c < nChunks; c += nWaves) {
    const int base = c << 4;
    const int arow = min(base + nsub, nN - 1);
    const float4 xa0 = *reinterpret_cast<const float4*>(x + (size_t)arow * 64 + kgrp);
    const float4 xa1 = *reinterpret_cast<const float4*>(x + (size_t)arow * 64 + kgrp + 4);
    const float4 xb0 = *reinterpret_cast<const float4*>(x + (size_t)arow * 64 + 32 + kgrp);
    const float4 xb1 = *reinterpret_cast<const float4*>(x + (size_t)arow * 64 + 36 + kgrp);
    bf16x8 a0, a1;
    a0[0] = (__bf16)xa0.x; a0[1] = (__bf16)xa0.y; a0[2] = (__bf16)xa0.z; a0[3] = (__bf16)xa0.w;
    a0[4] = (__bf16)xa1.x; a0[5] = (__bf16)xa1.y; a0[6] = (__bf16)xa1.z; a0[7] = (__bf16)xa1.w;
    a1[0] = (__bf16)xb0.x; a1[1] = (__bf16)xb0.y; a1[2] = (__bf16)xb0.z; a1[3] = (__bf16)xb0.w;
    a1[4] = (__bf16)xb1.x; a1[5] = (__bf16)xb1.y; a1[6] = (__bf16)xb1.z; a1[7] = (__bf16)xb1.w;
#pragma unroll
    for (int nt = 0; nt < 8; ++nt) {
      f32x4 acc = {bias[nt], bias[nt], bias[nt], bias[nt]};
      acc = __builtin_amdgcn_mfma_f32_16x16x32_bf16(a0, Bf[nt][0], acc, 0, 0, 0);
      acc = __builtin_amdgcn_mfma_f32_16x16x32_bf16(a1, Bf[nt][1], acc, 0, 0, 0);
      const int t = nt >> 2;
      const int o = ((nt & 3) << 4) + nsub;
      const int rbase = base + ((lane >> 4) << 2);
#pragma unroll
      for (int r = 0; r < 4; ++r) {
        const int node = rbase + r;
        if (node < nN)
          yb[((size_t)t * nN + node) * 64 + o] = bf_enc(f2bf(acc[r]));
      }
    }
  }
}

// ==================== deterministic two-level scatter ====================

// Phase 1: per-chunk-block LDS histogram of bins (no global atomics).
// countsT layout is bin-major: countsT[bin * NB_CHUNK + blk].
__global__ __launch_bounds__(1024) void k_lochist(const int* __restrict__ dst,
                                                  int* __restrict__ countsT,
                                                  int nE, int nBins, int chunk) {
  __shared__ int lh[MAXBINS];
  const int t = threadIdx.x;
  for (int i = t; i < nBins; i += 1024) lh[i] = 0;
  __syncthreads();
  const int beg = blockIdx.x * chunk;
  const int end = min(beg + chunk, nE);
  for (int i = beg + t; i < end; i += 1024) atomicAdd(&lh[dst[i] >> BIN_SHIFT], 1);
  __syncthreads();
  for (int i = t; i < nBins; i += 1024)
    countsT[(size_t)i * gridDim.x + blockIdx.x] = lh[i];
}

// Phase 2a: per-segment sums -> blockSums[SCAN_BLOCKS].
__global__ __launch_bounds__(256) void k_scan_partial(
    const int* __restrict__ counts, int* __restrict__ blockSums, int nN) {
  __shared__ int red[256];
  const int t = threadIdx.x;
  const int seg = (nN + gridDim.x - 1) / gridDim.x;
  const int beg = blockIdx.x * seg;
  const int end = min(beg + seg, nN);
  int s = 0;
  for (int i = beg + t; i < end; i += 256) s += counts[i];
  red[t] = s;
  __syncthreads();
  for (int d = 128; d > 0; d >>= 1) {
    if (t < d) red[t] += red[t + d];
    __syncthreads();
  }
  if (t == 0) blockSums[blockIdx.x] = red[0];
}

// Phase 2b: write exclusive offsets; each block locally scans blockSums
// (256 entries) to get its carry — k_scan_block launch eliminated.
__global__ __launch_bounds__(256) void k_scan_write(
    const int* __restrict__ counts, const int* __restrict__ blockSums,
    int* __restrict__ offs, int nN) {
  __shared__ int bs[256];
  __shared__ int sh[256];
  const int t = threadIdx.x;
  bs[t] = blockSums[t];
  __syncthreads();
  for (int d = 1; d < 256; d <<= 1) {  // inclusive scan, double-sync
    const int o = (t >= d) ? bs[t - d] : 0;
    __syncthreads();
    bs[t] += o;
    __syncthreads();
  }
  const int bid = blockIdx.x;
  int carry = (bid > 0) ? bs[bid - 1] : 0;
  const int total = bs[255];
  const int seg = (nN + gridDim.x - 1) / gridDim.x;
  const int beg = bid * seg;
  const int end = min(beg + seg, nN);
  for (int base = beg; base < end; base += 256) {
    const int i = base + t;
    const int v = (i < end) ? counts[i] : 0;
    sh[t] = v;
    __syncthreads();
    for (int d = 1; d < 256; d <<= 1) {
      const int o = (t >= d) ? sh[t - d] : 0;
      __syncthreads();
      sh[t] += o;
      __syncthreads();
    }
    if (i < end) offs[i] = carry + sh[t] - v;
    carry += sh[255];
    __syncthreads();
  }
  if (bid == gridDim.x - 1 && t == 0) offs[nN] = total;
}

// Phase 3: scatter records using deterministic per-(bin,blk) starts; only
// LDS cursor atomics. Record: src(0-19) | type(20) | dstLow(21-26).
__global__ __launch_bounds__(1024) void k_cscatter(
    const int* __restrict__ src, const int* __restrict__ dst,
    const int* __restrict__ ea, const int* __restrict__ offs,
    unsigned* __restrict__ rec, int nE, int nBins, int chunk) {
  __shared__ int cur[MAXBINS];
  const int t = threadIdx.x;
  for (int i = t; i < nBins; i += 1024)
    cur[i] = offs[(size_t)i * gridDim.x + blockIdx.x];
  __syncthreads();
  const int beg = blockIdx.x * chunk;
  const int end = min(beg + chunk, nE);
  for (int i = beg + t; i < end; i += 1024) {
    const int d = dst[i];
    const int pos = atomicAdd(&cur[d >> BIN_SHIFT], 1);
    rec[pos] = (unsigned)src[i] | ((unsigned)ea[i] << 20) |
               ((unsigned)(d & ((1 << BIN_SHIFT) - 1)) << 21);
  }
}

// ============================ reduction ============================
// One block per 64-node bin, EXACT record range, 8 waves (512 thr) split it.
// yb is ENC16: inner loop = load ushort, shl 16, single ds_atomic_max_u32 —
// branchless. acc init 0 = "untouched"; decode fuses the -inf -> 0 rule.
__global__ __launch_bounds__(512) void k_reduce_bin(
    const int* __restrict__ offs, const unsigned* __restrict__ rec,
    const unsigned short* __restrict__ yb, float* __restrict__ out, int nN) {
  __shared__ unsigned acc[64 * 64];  // 16 KB
  const int t = threadIdx.x;
#pragma unroll
  for (int i = 0; i < 8; ++i) acc[t + i * 512] = 0u;
  __syncthreads();

  const int bin = blockIdx.x;
  const int beg = offs[bin * NB_CHUNK];
  const int cnt = offs[(bin + 1) * NB_CHUNK] - beg;
  const int w = t >> 6;
  const unsigned lane = t & 63;
  const unsigned nNu = (unsigned)nN;
  const int myBeg = beg + ((cnt * w) >> 3);
  const int myEnd = beg + ((cnt * (w + 1)) >> 3);

  int j = myBeg;
  for (; j + 7 < myEnd; j += 8) {
    unsigned r[8];
    unsigned v[8];
#pragma unroll
    for (int q = 0; q < 8; ++q) r[q] = rec[j + q];
#pragma unroll
    for (int q = 0; q < 8; ++q)
      v[q] = (unsigned)yb[((((r[q] >> 20) & 1u) * nNu + (r[q] & 0xFFFFFu)) << 6) + lane] << 16;
#pragma unroll
    for (int q = 0; q < 8; ++q)
      atomicMax(&acc[(((r[q] >> 21) & 63u) << 6) + lane], v[q]);
  }
  for (; j < myEnd; ++j) {
    const unsigned r0 = rec[j];
    const unsigned v0 =
        (unsigned)yb[((((r0 >> 20) & 1u) * nNu + (r0 & 0xFFFFFu)) << 6) + lane] << 16;
    atomicMax(&acc[(((r0 >> 21) & 63u) << 6) + lane], v0);
  }
  __syncthreads();

  const int nodeBase = bin << 6;
  for (int f = t; f < 64 * 16; f += 512) {  // one float4 per f
    const int node = nodeBase + (f >> 4);
    if (node < nN) {
      float4 v;
      v.x = bf_dec_to_f32(acc[f * 4 + 0]);
      v.y = bf_dec_to_f32(acc[f * 4 + 1]);
      v.z = bf_dec_to_f32(acc[f * 4 + 2]);
      v.w = bf_dec_to_f32(acc[f * 4 + 3]);
      *reinterpret_cast<float4*>(&out[(size_t)node * 64 + (f & 15) * 4]) = v;
    }
  }
}

// ============================ fallback kernels ============================

__global__ void k_fixup(float4* __restrict__ out, int n4) {
  int i = blockIdx.x * blockDim.x + threadIdx.x;
  if (i < n4) {
    float4 v = out[i];
    if (v.x == -INFINITY) v.x = 0.0f;
    if (v.y == -INFINITY) v.y = 0.0f;
    if (v.z == -INFINITY) v.z = 0.0f;
    if (v.w == -INFINITY) v.w = 0.0f;
    out[i] = v;
  }
}

__global__ __launch_bounds__(256) void k_edge_direct(
    const float* __restrict__ x, const float* __restrict__ W,
    const float* __restrict__ b, const int* __restrict__ ei,
    const int* __restrict__ ea, float* __restrict__ out, int nEdges) {
  __shared__ float Wl[2 * D * D];
  __shared__ float bl[2 * D];
  for (int i = threadIdx.x; i < 2 * D * D; i += 256) Wl[i] = W[i];
  for (int i = threadIdx.x; i < 2 * D; i += 256) bl[i] = b[i];
  __syncthreads();
  const int wave = threadIdx.x >> 6;
  const int lane = threadIdx.x & 63;
  for (int e = blockIdx.x * 4 + wave; e < nEdges; e += gridDim.x * 4) {
    const int src = ei[e];
    const int dst = ei[nEdges + e];
    const int t = ea[e];
    const float xk = x[(size_t)src * D + lane];
    float acc = bl[t * D + lane];
    const float* Wt = &Wl[t * D * D];
#pragma unroll
    for (int k = 0; k < D; ++k)
      acc = fmaf(__shfl(xk, k, 64), Wt[k * D + lane], acc);
    float* p = out + (size_t)dst * D + lane;
    const float cur = *p;
    atomic_max_float(p, acc, cur);
  }
}

// ============================ launcher ============================

extern "C" void kernel_launch(void* const* d_in, const int* in_sizes, int n_in,
                              void* d_out, int out_size, void* d_ws, size_t ws_size,
                              hipStream_t stream) {
  const float* x = (const float*)d_in[0];
  const float* W = (const float*)d_in[1];
  const float* b = (const float*)d_in[2];
  const int* ei = (const int*)d_in[3];   // [2, E]: src row then dst row
  const int* ea = (const int*)d_in[4];   // [E]
  float* out = (float*)d_out;

  const int nNodes = in_sizes[0] / D;
  const int nEdges = in_sizes[4];
  const int n4out = (nNodes * D) / 4;
  const int nBins = (nNodes + (1 << BIN_SHIFT) - 1) >> BIN_SHIFT;
  const int nScan = nBins * NB_CHUNK;
  const int chunk = (nEdges + NB_CHUNK - 1) / NB_CHUNK;

  // Workspace carve (256B-aligned regions).
  auto rup = [](size_t v) { return (v + 255) & ~(size_t)255; };
  const size_t ybB = (size_t)2 * nNodes * D * sizeof(unsigned short);
  const size_t offYb = 0;
  const size_t offCT = rup(offYb + ybB);
  const size_t offOffs = rup(offCT + (size_t)nScan * sizeof(int));
  const size_t offBS = rup(offOffs + (size_t)(nScan + 1) * sizeof(int));
  const size_t offRec = rup(offBS + (size_t)SCAN_BLOCKS * sizeof(int));
  const size_t need = offRec + (size_t)nEdges * sizeof(unsigned);

  if (ws_size >= need && nNodes < (1 << 20) && nBins <= MAXBINS) {
    // ---- bf16 MFMA + deterministic two-level scatter path ----
    char* ws = (char*)d_ws;
    unsigned short* yb = (unsigned short*)(ws + offYb);
    int* countsT = (int*)(ws + offCT);
    int* offs = (int*)(ws + offOffs);
    int* blockSums = (int*)(ws + offBS);
    unsigned* rec = (unsigned*)(ws + offRec);

    const int* srcRow = ei;
    const int* dstRow = ei + nEdges;

    k_lochist<<<NB_CHUNK, 1024, 0, stream>>>(dstRow, countsT, nEdges, nBins, chunk);
    k_scan_partial<<<SCAN_BLOCKS, 256, 0, stream>>>(countsT, blockSums, nScan);
    k_scan_write<<<SCAN_BLOCKS, 256, 0, stream>>>(countsT, blockSums, offs, nScan);
    k_cscatter<<<NB_CHUNK, 1024, 0, stream>>>(srcRow, dstRow, ea, offs, rec,
                                              nEdges, nBins, chunk);
    k_gemm<<<512, 256, 0, stream>>>(x, W, b, yb, nNodes);
    k_reduce_bin<<<nBins, 512, 0, stream>>>(offs, rec, yb, out, nNodes);
  } else {
    // ---- fallback: direct edge compute with filtered atomics ----
    k_init_neginf<<<(n4out + 255) / 256, 256, 0, stream>>>((float4*)out, n4out);
    k_edge_direct<<<4096, 256, 0, stream>>>(x, W, b, ei, ea, out, nEdges);
    k_fixup<<<(n4out + 255) / 256, 256, 0, stream>>>((float4*)out, n4out);
  }
}